// Round 1
// baseline (517.996 us; speedup 1.0000x reference)
//
#include <hip/hip_runtime.h>
#include <hip/hip_bf16.h>

#define N_POINTS 1000000
#define FEAT 64
#define BSEG 128
#define EPS 1e-5f
#define CHUNK 2048
#define NBLK_SEG ((N_POINTS + CHUNK - 1) / CHUNK)   // 489

// ---- ordered-uint encoding for float atomic max ----
__device__ __forceinline__ unsigned ordered_enc(float f) {
    unsigned u = __float_as_uint(f);
    return (u & 0x80000000u) ? ~u : (u | 0x80000000u);
}
__device__ __forceinline__ float ordered_dec(unsigned v) {
    unsigned u = (v & 0x80000000u) ? (v & 0x7fffffffu) : ~v;
    return __uint_as_float(u);
}

// encode(-inf) = ~0xFF800000 = 0x007FFFFF
#define ENC_NEG_INF 0x007FFFFFu

__global__ void k_init(unsigned* __restrict__ pool) {
    int i = blockIdx.x * blockDim.x + threadIdx.x;
    if (i < BSEG * FEAT) pool[i] = ENC_NEG_INF;
}

// ---- segment max: each block handles a contiguous chunk of sorted points ----
__global__ __launch_bounds__(256) void k_segmax(const float4* __restrict__ feat,
                                                const int* __restrict__ batch,
                                                unsigned* __restrict__ pool) {
    __shared__ unsigned short sb[CHUNK];
    __shared__ unsigned spool[4 * FEAT];   // up to 4 distinct segments per chunk
    const int t = threadIdx.x;
    const int base = blockIdx.x * CHUNK;
    int rem = N_POINTS - base;
    if (rem > CHUNK) rem = CHUNK;

    for (int i = t; i < CHUNK; i += 256)
        sb[i] = (i < rem) ? (unsigned short)batch[base + i] : (unsigned short)0xFFFF;
    spool[t] = 0u;   // 256 entries == 4*FEAT
    __syncthreads();

    const int seg0 = sb[0];
    const int q = t & 15;       // feature quad (16 x float4 = 64 feats)
    const int r = t >> 4;       // point-group lane

    float4 m = make_float4(-INFINITY, -INFINITY, -INFINITY, -INFINITY);
    int cur = -1;

    auto flush = [&](int seg, float4 mm) {
        unsigned e0 = ordered_enc(mm.x), e1 = ordered_enc(mm.y);
        unsigned e2 = ordered_enc(mm.z), e3 = ordered_enc(mm.w);
        int slot = seg - seg0;
        if (slot >= 0 && slot < 4) {
            unsigned* p = &spool[slot * FEAT + q * 4];
            atomicMax(&p[0], e0); atomicMax(&p[1], e1);
            atomicMax(&p[2], e2); atomicMax(&p[3], e3);
        } else {
            unsigned* p = &pool[seg * FEAT + q * 4];
            atomicMax(&p[0], e0); atomicMax(&p[1], e1);
            atomicMax(&p[2], e2); atomicMax(&p[3], e3);
        }
    };

    for (int i = r; i < rem; i += 16) {
        int seg = sb[i];
        if (seg != cur) {
            if (cur >= 0) flush(cur, m);
            cur = seg;
            m = make_float4(-INFINITY, -INFINITY, -INFINITY, -INFINITY);
        }
        float4 v = feat[(base + i) * 16 + q];
        m.x = fmaxf(m.x, v.x); m.y = fmaxf(m.y, v.y);
        m.z = fmaxf(m.z, v.z); m.w = fmaxf(m.w, v.w);
    }
    if (cur >= 0) flush(cur, m);
    __syncthreads();

    // drain LDS table -> global (only touched entries)
    unsigned v = spool[t];
    if (v != 0u) {
        int slot = t >> 6;
        int seg = seg0 + slot;
        atomicMax(&pool[seg * FEAT + (t & 63)], v);
    }
}

// ---- fused LayerNorm + proj + fc1 + fc2 : one block per row ----
__global__ __launch_bounds__(256) void k_mlp(const unsigned* __restrict__ pool,
                                             const float* __restrict__ ln_g,
                                             const float* __restrict__ ln_b,
                                             const float* __restrict__ pw,
                                             const float* __restrict__ pb,
                                             const float* __restrict__ w1,
                                             const float* __restrict__ b1,
                                             const float* __restrict__ w2,
                                             const float* __restrict__ b2,
                                             float* __restrict__ h2out) {
    __shared__ float xn[64];
    __shared__ float lat[512];
    __shared__ float h1s[256];
    const int b = blockIdx.x, t = threadIdx.x;

    if (t < 64) {
        float x = ordered_dec(pool[b * 64 + t]);
        float s = x;
        #pragma unroll
        for (int off = 32; off > 0; off >>= 1) s += __shfl_xor(s, off, 64);
        float mu = s * (1.0f / 64.0f);
        float d = x - mu;
        float s2 = d * d;
        #pragma unroll
        for (int off = 32; off > 0; off >>= 1) s2 += __shfl_xor(s2, off, 64);
        float var = s2 * (1.0f / 64.0f);
        xn[t] = d * rsqrtf(var + EPS) * ln_g[t] + ln_b[t];
    }
    __syncthreads();

    // latent = xn @ proj_w + proj_b  (512 outputs, 2 per thread)
    {
        float a0 = pb[t], a1 = pb[t + 256];
        #pragma unroll 8
        for (int j = 0; j < 64; ++j) {
            float xj = xn[j];
            a0 = fmaf(xj, pw[j * 512 + t], a0);
            a1 = fmaf(xj, pw[j * 512 + t + 256], a1);
        }
        lat[t] = a0; lat[t + 256] = a1;
    }
    __syncthreads();

    // h1 = relu(lat @ w1 + b1)  (256 outputs)
    {
        float a = b1[t];
        #pragma unroll 8
        for (int j = 0; j < 512; ++j)
            a = fmaf(lat[j], w1[j * 256 + t], a);
        h1s[t] = fmaxf(a, 0.0f);
    }
    __syncthreads();

    // h2 = relu(h1 @ w2 + b2)  (512 outputs, 2 per thread)
    {
        float a0 = b2[t], a1 = b2[t + 256];
        #pragma unroll 8
        for (int j = 0; j < 256; ++j) {
            float hj = h1s[j];
            a0 = fmaf(hj, w2[j * 512 + t], a0);
            a1 = fmaf(hj, w2[j * 512 + t + 256], a1);
        }
        h2out[b * 512 + t] = fmaxf(a0, 0.0f);
        h2out[b * 512 + t + 256] = fmaxf(a1, 0.0f);
    }
}

// ---- final GEMM: out[128,6144] = h2[128,512] @ w3[512,6144] + b3 ----
#define FS 132   // LDS row stride (pad 128 -> 132)
__global__ __launch_bounds__(256) void k_final(const float* __restrict__ h2,
                                               const float* __restrict__ w3,
                                               const float* __restrict__ b3,
                                               float* __restrict__ out) {
    __shared__ float sh[64 * FS];   // 33 KB: 64 rows x 128 k chunk
    const int t = threadIdx.x;
    const int cp = blockIdx.x, rp = blockIdx.y;
    const int rbase = rp * 64;
    const int tx = t & 15, ty = t >> 4;
    const int c = cp * 64 + tx * 4;
    const int r0 = ty * 4;

    float4 bias = *(const float4*)&b3[c];
    float4 acc[4] = {bias, bias, bias, bias};

    const float4* h2g = (const float4*)h2;
    for (int kc = 0; kc < 512; kc += 128) {
        __syncthreads();
        #pragma unroll
        for (int it = 0; it < 8; ++it) {
            int idx = it * 256 + t;
            int r = idx >> 5;       // 32 float4 per row-chunk
            int kq = idx & 31;
            float4 v = h2g[(rbase + r) * 128 + (kc >> 2) + kq];
            *(float4*)&sh[r * FS + kq * 4] = v;
        }
        __syncthreads();
        for (int kb = 0; kb < 128; kb += 4) {
            float4 a[4];
            #pragma unroll
            for (int i = 0; i < 4; ++i)
                a[i] = *(const float4*)&sh[(r0 + i) * FS + kb];
            #pragma unroll
            for (int kk = 0; kk < 4; ++kk) {
                float4 w = *(const float4*)&w3[(kc + kb + kk) * 6144 + c];
                #pragma unroll
                for (int i = 0; i < 4; ++i) {
                    float e = (kk == 0) ? a[i].x : (kk == 1) ? a[i].y
                            : (kk == 2) ? a[i].z : a[i].w;
                    acc[i].x = fmaf(e, w.x, acc[i].x);
                    acc[i].y = fmaf(e, w.y, acc[i].y);
                    acc[i].z = fmaf(e, w.z, acc[i].z);
                    acc[i].w = fmaf(e, w.w, acc[i].w);
                }
            }
        }
    }
    #pragma unroll
    for (int i = 0; i < 4; ++i)
        *(float4*)&out[(rbase + r0 + i) * 6144 + c] = acc[i];
}

extern "C" void kernel_launch(void* const* d_in, const int* in_sizes, int n_in,
                              void* d_out, int out_size, void* d_ws, size_t ws_size,
                              hipStream_t stream) {
    const float* feat  = (const float*)d_in[0];
    const int*   batch = (const int*)d_in[1];
    const float* ln_g  = (const float*)d_in[2];
    const float* ln_b  = (const float*)d_in[3];
    const float* pw    = (const float*)d_in[4];
    const float* pb    = (const float*)d_in[5];
    const float* w1    = (const float*)d_in[6];
    const float* b1    = (const float*)d_in[7];
    const float* w2    = (const float*)d_in[8];
    const float* b2    = (const float*)d_in[9];
    const float* w3    = (const float*)d_in[10];
    const float* b3    = (const float*)d_in[11];
    float* out = (float*)d_out;

    unsigned* pool = (unsigned*)d_ws;            // 128*64 uints
    float* h2buf = (float*)d_ws + BSEG * FEAT;   // 128*512 floats

    k_init<<<(BSEG * FEAT + 255) / 256, 256, 0, stream>>>(pool);
    k_segmax<<<NBLK_SEG, 256, 0, stream>>>((const float4*)feat, batch, pool);
    k_mlp<<<BSEG, 256, 0, stream>>>(pool, ln_g, ln_b, pw, pb, w1, b1, w2, b2, h2buf);
    k_final<<<dim3(96, 2), 256, 0, stream>>>(h2buf, w3, b3, out);
}

// Round 2
// 503.078 us; speedup vs baseline: 1.0297x; 1.0297x over previous
//
#include <hip/hip_runtime.h>
#include <hip/hip_bf16.h>

#define N_POINTS 1000000
#define FEAT 64
#define BSEG 128
#define EPS 1e-5f
#define CHUNK 1024
#define NBLK_SEG ((N_POINTS + CHUNK - 1) / CHUNK)   // 977

// ---- ordered-uint encoding for float atomic max ----
__device__ __forceinline__ unsigned ordered_enc(float f) {
    unsigned u = __float_as_uint(f);
    return (u & 0x80000000u) ? ~u : (u | 0x80000000u);
}
__device__ __forceinline__ float ordered_dec(unsigned v) {
    unsigned u = (v & 0x80000000u) ? (v & 0x7fffffffu) : ~v;
    return __uint_as_float(u);
}

#define ENC_NEG_INF 0x007FFFFFu   // ordered_enc(-inf)

__global__ void k_init(unsigned* __restrict__ pool) {
    int i = blockIdx.x * blockDim.x + threadIdx.x;
    if (i < BSEG * FEAT) pool[i] = ENC_NEG_INF;
}

// ---- segment max over sorted batch ids ----
// block = 1024-point chunk; thread = (point-lane r 0..31) x (32B feature octet q 0..7)
// 32 B/lane/iter keeps ~30 KB in flight per CU (vs ~9 KB needed at HBM latency).
__global__ __launch_bounds__(256) void k_segmax(const float4* __restrict__ feat,
                                                const int* __restrict__ batch,
                                                unsigned* __restrict__ pool) {
    __shared__ unsigned short sb[CHUNK];
    __shared__ unsigned spool[4 * FEAT];   // 4 segment slots per chunk (1024-pt chunk spans <=2 w.h.p.)
    const int t = threadIdx.x;
    const int base = blockIdx.x * CHUNK;
    int rem = N_POINTS - base;
    if (rem > CHUNK) rem = CHUNK;

    for (int i = t; i < CHUNK; i += 256)
        sb[i] = (i < rem) ? (unsigned short)batch[base + i] : (unsigned short)0xFFFF;
    spool[t] = 0u;   // 256 entries == 4*FEAT
    __syncthreads();

    const int seg0 = sb[0];
    const int q = t & 7;        // which 32 B (8 floats) of the 256 B point
    const int r = t >> 3;       // point lane 0..31

    float4 m0 = make_float4(-INFINITY, -INFINITY, -INFINITY, -INFINITY);
    float4 m1 = m0;
    int cur = -1;

    auto flush = [&](int seg, float4 a, float4 b) {
        unsigned e[8] = { ordered_enc(a.x), ordered_enc(a.y), ordered_enc(a.z), ordered_enc(a.w),
                          ordered_enc(b.x), ordered_enc(b.y), ordered_enc(b.z), ordered_enc(b.w) };
        int slot = seg - seg0;
        if (slot >= 0 && slot < 4) {
            unsigned* p = &spool[slot * FEAT + q * 8];
            #pragma unroll
            for (int j = 0; j < 8; ++j) atomicMax(&p[j], e[j]);
        } else {
            unsigned* p = &pool[seg * FEAT + q * 8];
            #pragma unroll
            for (int j = 0; j < 8; ++j) atomicMax(&p[j], e[j]);
        }
    };

    for (int i = r; i < rem; i += 32) {
        const float4* p = &feat[(size_t)(base + i) * 16 + q * 2];
        float4 v0 = p[0];
        float4 v1 = p[1];
        int seg = sb[i];
        if (seg != cur) {
            if (cur >= 0) flush(cur, m0, m1);
            cur = seg;
            m0 = make_float4(-INFINITY, -INFINITY, -INFINITY, -INFINITY);
            m1 = m0;
        }
        m0.x = fmaxf(m0.x, v0.x); m0.y = fmaxf(m0.y, v0.y);
        m0.z = fmaxf(m0.z, v0.z); m0.w = fmaxf(m0.w, v0.w);
        m1.x = fmaxf(m1.x, v1.x); m1.y = fmaxf(m1.y, v1.y);
        m1.z = fmaxf(m1.z, v1.z); m1.w = fmaxf(m1.w, v1.w);
    }
    if (cur >= 0) flush(cur, m0, m1);
    __syncthreads();

    unsigned v = spool[t];
    if (v != 0u) {
        int slot = t >> 6;
        atomicMax(&pool[(seg0 + slot) * FEAT + (t & 63)], v);
    }
}

// ---- fused LayerNorm + proj + fc1 + fc2 : one block per row ----
__global__ __launch_bounds__(256) void k_mlp(const unsigned* __restrict__ pool,
                                             const float* __restrict__ ln_g,
                                             const float* __restrict__ ln_b,
                                             const float* __restrict__ pw,
                                             const float* __restrict__ pb,
                                             const float* __restrict__ w1,
                                             const float* __restrict__ b1,
                                             const float* __restrict__ w2,
                                             const float* __restrict__ b2,
                                             float* __restrict__ h2out) {
    __shared__ float xn[64];
    __shared__ float lat[512];
    __shared__ float h1s[256];
    const int b = blockIdx.x, t = threadIdx.x;

    if (t < 64) {
        float x = ordered_dec(pool[b * 64 + t]);
        float s = x;
        #pragma unroll
        for (int off = 32; off > 0; off >>= 1) s += __shfl_xor(s, off, 64);
        float mu = s * (1.0f / 64.0f);
        float d = x - mu;
        float s2 = d * d;
        #pragma unroll
        for (int off = 32; off > 0; off >>= 1) s2 += __shfl_xor(s2, off, 64);
        float var = s2 * (1.0f / 64.0f);
        xn[t] = d * rsqrtf(var + EPS) * ln_g[t] + ln_b[t];
    }
    __syncthreads();

    {
        float a0 = pb[t], a1 = pb[t + 256];
        #pragma unroll 8
        for (int j = 0; j < 64; ++j) {
            float xj = xn[j];
            a0 = fmaf(xj, pw[j * 512 + t], a0);
            a1 = fmaf(xj, pw[j * 512 + t + 256], a1);
        }
        lat[t] = a0; lat[t + 256] = a1;
    }
    __syncthreads();

    {
        float a = b1[t];
        #pragma unroll 8
        for (int j = 0; j < 512; ++j)
            a = fmaf(lat[j], w1[j * 256 + t], a);
        h1s[t] = fmaxf(a, 0.0f);
    }
    __syncthreads();

    {
        float a0 = b2[t], a1 = b2[t + 256];
        #pragma unroll 8
        for (int j = 0; j < 256; ++j) {
            float hj = h1s[j];
            a0 = fmaf(hj, w2[j * 512 + t], a0);
            a1 = fmaf(hj, w2[j * 512 + t + 256], a1);
        }
        h2out[b * 512 + t] = fmaxf(a0, 0.0f);
        h2out[b * 512 + t + 256] = fmaxf(a1, 0.0f);
    }
}

// ---- final GEMM: out[128,6144] = h2[128,512] @ w3[512,6144] + b3 ----
// One block per 64-col panel covering ALL 128 rows -> w3 read exactly once.
// 512 threads: tx 0..15 (col quad), ty 0..31 (rows ty*4..+3). 4x4 accs/thread.
#define RS 136   // LDS row stride: 16B-aligned float4 stores, conflict-free b32 reads
__global__ __launch_bounds__(512) void k_final(const float* __restrict__ h2,
                                               const float* __restrict__ w3,
                                               const float* __restrict__ b3,
                                               float* __restrict__ out) {
    __shared__ float h2s[128 * RS];   // 69.6 KB
    const int t = threadIdx.x;
    const int tx = t & 15;
    const int ty = t >> 4;
    const int c = blockIdx.x * 64 + tx * 4;
    const int r0 = ty * 4;

    float4 bias = *(const float4*)&b3[c];
    float4 acc[4] = {bias, bias, bias, bias};

    const float4* h2g = (const float4*)h2;
    for (int kc = 0; kc < 512; kc += 128) {
        __syncthreads();
        #pragma unroll
        for (int it = 0; it < 8; ++it) {
            int idx = it * 512 + t;
            int rr = idx >> 5;        // 32 float4 per row-chunk
            int kq = idx & 31;
            float4 v = h2g[rr * 128 + (kc >> 2) + kq];
            *(float4*)&h2s[rr * RS + kq * 4] = v;
        }
        __syncthreads();
        #pragma unroll 4
        for (int k = 0; k < 128; ++k) {
            float4 w = *(const float4*)&w3[(size_t)(kc + k) * 6144 + c];
            float a0 = h2s[(r0 + 0) * RS + k];
            float a1 = h2s[(r0 + 1) * RS + k];
            float a2 = h2s[(r0 + 2) * RS + k];
            float a3 = h2s[(r0 + 3) * RS + k];
            acc[0].x = fmaf(a0, w.x, acc[0].x); acc[0].y = fmaf(a0, w.y, acc[0].y);
            acc[0].z = fmaf(a0, w.z, acc[0].z); acc[0].w = fmaf(a0, w.w, acc[0].w);
            acc[1].x = fmaf(a1, w.x, acc[1].x); acc[1].y = fmaf(a1, w.y, acc[1].y);
            acc[1].z = fmaf(a1, w.z, acc[1].z); acc[1].w = fmaf(a1, w.w, acc[1].w);
            acc[2].x = fmaf(a2, w.x, acc[2].x); acc[2].y = fmaf(a2, w.y, acc[2].y);
            acc[2].z = fmaf(a2, w.z, acc[2].z); acc[2].w = fmaf(a2, w.w, acc[2].w);
            acc[3].x = fmaf(a3, w.x, acc[3].x); acc[3].y = fmaf(a3, w.y, acc[3].y);
            acc[3].z = fmaf(a3, w.z, acc[3].z); acc[3].w = fmaf(a3, w.w, acc[3].w);
        }
    }
    #pragma unroll
    for (int i = 0; i < 4; ++i)
        *(float4*)&out[(size_t)(r0 + i) * 6144 + c] = acc[i];
}

extern "C" void kernel_launch(void* const* d_in, const int* in_sizes, int n_in,
                              void* d_out, int out_size, void* d_ws, size_t ws_size,
                              hipStream_t stream) {
    const float* feat  = (const float*)d_in[0];
    const int*   batch = (const int*)d_in[1];
    const float* ln_g  = (const float*)d_in[2];
    const float* ln_b  = (const float*)d_in[3];
    const float* pw    = (const float*)d_in[4];
    const float* pb    = (const float*)d_in[5];
    const float* w1    = (const float*)d_in[6];
    const float* b1    = (const float*)d_in[7];
    const float* w2    = (const float*)d_in[8];
    const float* b2    = (const float*)d_in[9];
    const float* w3    = (const float*)d_in[10];
    const float* b3    = (const float*)d_in[11];
    float* out = (float*)d_out;

    unsigned* pool = (unsigned*)d_ws;            // 128*64 uints
    float* h2buf = (float*)d_ws + BSEG * FEAT;   // 128*512 floats

    k_init<<<(BSEG * FEAT + 255) / 256, 256, 0, stream>>>(pool);
    k_segmax<<<NBLK_SEG, 256, 0, stream>>>((const float4*)feat, batch, pool);
    k_mlp<<<BSEG, 256, 0, stream>>>(pool, ln_g, ln_b, pw, pb, w1, b1, w2, b2, h2buf);
    k_final<<<96, 512, 0, stream>>>(h2buf, w3, b3, out);
}

// Round 3
// 472.557 us; speedup vs baseline: 1.0962x; 1.0646x over previous
//
#include <hip/hip_runtime.h>
#include <hip/hip_bf16.h>

#define N_POINTS 1000000
#define FEAT 64
#define BSEG 128
#define EPS 1e-5f
#define CHUNK 1024
#define NBLK_SEG ((N_POINTS + CHUNK - 1) / CHUNK)   // 977

// ---- biased ordered-uint encoding for float atomic max ----
// enc(x) = ordered(x) - ordered(-inf)  =>  enc(-inf) = 0, so init is memset(0).
#define ENC_BIAS 0x007FFFFFu   // ordered(-inf)

__device__ __forceinline__ unsigned ordered_enc(float f) {
    unsigned u = __float_as_uint(f);
    unsigned o = (u & 0x80000000u) ? ~u : (u | 0x80000000u);
    return o - ENC_BIAS;
}
__device__ __forceinline__ float ordered_dec(unsigned v) {
    unsigned o = v + ENC_BIAS;
    unsigned u = (o & 0x80000000u) ? (o & 0x7fffffffu) : ~o;
    return __uint_as_float(u);
}

// ---- segment max over sorted batch ids ----
// block = 1024-point chunk; thread = (point-lane r 0..31) x (32B feature octet q 0..7)
__global__ __launch_bounds__(256) void k_segmax(const float4* __restrict__ feat,
                                                const int* __restrict__ batch,
                                                unsigned* __restrict__ pool) {
    __shared__ unsigned short sb[CHUNK];
    __shared__ unsigned spool[4 * FEAT];
    const int t = threadIdx.x;
    const int base = blockIdx.x * CHUNK;
    int rem = N_POINTS - base;
    if (rem > CHUNK) rem = CHUNK;

    for (int i = t; i < CHUNK; i += 256)
        sb[i] = (i < rem) ? (unsigned short)batch[base + i] : (unsigned short)0xFFFF;
    spool[t] = 0u;   // 256 entries == 4*FEAT; 0 == enc(-inf)
    __syncthreads();

    const int seg0 = sb[0];
    const int q = t & 7;
    const int r = t >> 3;

    float4 m0 = make_float4(-INFINITY, -INFINITY, -INFINITY, -INFINITY);
    float4 m1 = m0;
    int cur = -1;

    auto flush = [&](int seg, float4 a, float4 b) {
        unsigned e[8] = { ordered_enc(a.x), ordered_enc(a.y), ordered_enc(a.z), ordered_enc(a.w),
                          ordered_enc(b.x), ordered_enc(b.y), ordered_enc(b.z), ordered_enc(b.w) };
        int slot = seg - seg0;
        if (slot >= 0 && slot < 4) {
            unsigned* p = &spool[slot * FEAT + q * 8];
            #pragma unroll
            for (int j = 0; j < 8; ++j) atomicMax(&p[j], e[j]);
        } else {
            unsigned* p = &pool[seg * FEAT + q * 8];
            #pragma unroll
            for (int j = 0; j < 8; ++j) atomicMax(&p[j], e[j]);
        }
    };

    for (int i = r; i < rem; i += 32) {
        const float4* p = &feat[(size_t)(base + i) * 16 + q * 2];
        float4 v0 = p[0];
        float4 v1 = p[1];
        int seg = sb[i];
        if (seg != cur) {
            if (cur >= 0) flush(cur, m0, m1);
            cur = seg;
            m0 = make_float4(-INFINITY, -INFINITY, -INFINITY, -INFINITY);
            m1 = m0;
        }
        m0.x = fmaxf(m0.x, v0.x); m0.y = fmaxf(m0.y, v0.y);
        m0.z = fmaxf(m0.z, v0.z); m0.w = fmaxf(m0.w, v0.w);
        m1.x = fmaxf(m1.x, v1.x); m1.y = fmaxf(m1.y, v1.y);
        m1.z = fmaxf(m1.z, v1.z); m1.w = fmaxf(m1.w, v1.w);
    }
    if (cur >= 0) flush(cur, m0, m1);
    __syncthreads();

    unsigned v = spool[t];
    if (v != 0u) {
        int slot = t >> 6;
        atomicMax(&pool[(seg0 + slot) * FEAT + (t & 63)], v);
    }
}

// ---- fused LayerNorm + proj + fc1 + fc2 : one block per row, 1024 threads ----
// Reduction dims split across threads (2/4/2-way) to shorten the per-thread
// serial load chain: 832 -> 288 latency-bound L2 loads.
__global__ __launch_bounds__(1024) void k_mlp(const unsigned* __restrict__ pool,
                                              const float* __restrict__ ln_g,
                                              const float* __restrict__ ln_b,
                                              const float* __restrict__ pw,
                                              const float* __restrict__ pb,
                                              const float* __restrict__ w1,
                                              const float* __restrict__ b1,
                                              const float* __restrict__ w2,
                                              const float* __restrict__ b2,
                                              float* __restrict__ h2out) {
    __shared__ float xn[64];
    __shared__ float lat[512];
    __shared__ float h1s[256];
    __shared__ float red[1024];
    const int b = blockIdx.x, t = threadIdx.x;

    if (t < 64) {
        float x = ordered_dec(pool[b * 64 + t]);
        float s = x;
        #pragma unroll
        for (int off = 32; off > 0; off >>= 1) s += __shfl_xor(s, off, 64);
        float mu = s * (1.0f / 64.0f);
        float d = x - mu;
        float s2 = d * d;
        #pragma unroll
        for (int off = 32; off > 0; off >>= 1) s2 += __shfl_xor(s2, off, 64);
        float var = s2 * (1.0f / 64.0f);
        xn[t] = d * rsqrtf(var + EPS) * ln_g[t] + ln_b[t];
    }
    __syncthreads();

    // proj: 512 outputs x 2-way k-split (k=64)
    {
        int o = t & 511, h = t >> 9;
        float a = 0.0f;
        #pragma unroll
        for (int j = 0; j < 32; ++j) {
            int k = h * 32 + j;
            a = fmaf(xn[k], pw[k * 512 + o], a);
        }
        red[t] = a;
    }
    __syncthreads();
    if (t < 512) lat[t] = red[t] + red[t + 512] + pb[t];
    __syncthreads();

    // fc1: 256 outputs x 4-way k-split (k=512)
    {
        int o = t & 255, h = t >> 8;
        float a = 0.0f;
        #pragma unroll 8
        for (int j = 0; j < 128; ++j) {
            int k = h * 128 + j;
            a = fmaf(lat[k], w1[k * 256 + o], a);
        }
        red[t] = a;
    }
    __syncthreads();
    if (t < 256)
        h1s[t] = fmaxf(red[t] + red[t + 256] + red[t + 512] + red[t + 768] + b1[t], 0.0f);
    __syncthreads();

    // fc2: 512 outputs x 2-way k-split (k=256)
    {
        int o = t & 511, h = t >> 9;
        float a = 0.0f;
        #pragma unroll 8
        for (int j = 0; j < 128; ++j) {
            int k = h * 128 + j;
            a = fmaf(h1s[k], w2[k * 512 + o], a);
        }
        red[t] = a;
    }
    __syncthreads();
    if (t < 512)
        h2out[b * 512 + t] = fmaxf(red[t] + red[t + 512] + b2[t], 0.0f);
}

// ---- final GEMM: out[128,6144] = h2[128,512] @ w3[512,6144] + b3 ----
// One block per 64-col panel covering ALL 128 rows -> w3 read exactly once.
// k unrolled by 4 so each LDS row read is a single ds_read_b128 (RS=136 keeps
// 16B alignment for k%4==0 and breaks pow-2 bank stride).
#define RS 136
__global__ __launch_bounds__(512) void k_final(const float* __restrict__ h2,
                                               const float* __restrict__ w3,
                                               const float* __restrict__ b3,
                                               float* __restrict__ out) {
    __shared__ float h2s[128 * RS];   // 69.6 KB
    const int t = threadIdx.x;
    const int tx = t & 15;
    const int ty = t >> 4;
    const int c = blockIdx.x * 64 + tx * 4;
    const int r0 = ty * 4;

    float4 bias = *(const float4*)&b3[c];
    float4 acc[4] = {bias, bias, bias, bias};

    const float4* h2g = (const float4*)h2;
    for (int kc = 0; kc < 512; kc += 128) {
        __syncthreads();
        #pragma unroll
        for (int it = 0; it < 8; ++it) {
            int idx = it * 512 + t;
            int rr = idx >> 5;        // 32 float4 per row-chunk
            int kq = idx & 31;
            float4 v = h2g[rr * 128 + (kc >> 2) + kq];
            *(float4*)&h2s[rr * RS + kq * 4] = v;
        }
        __syncthreads();
        for (int k = 0; k < 128; k += 4) {
            float4 A0 = *(const float4*)&h2s[(r0 + 0) * RS + k];
            float4 A1 = *(const float4*)&h2s[(r0 + 1) * RS + k];
            float4 A2 = *(const float4*)&h2s[(r0 + 2) * RS + k];
            float4 A3 = *(const float4*)&h2s[(r0 + 3) * RS + k];
            #pragma unroll
            for (int kk = 0; kk < 4; ++kk) {
                float4 w = *(const float4*)&w3[(size_t)(kc + k + kk) * 6144 + c];
                float a0 = (kk == 0) ? A0.x : (kk == 1) ? A0.y : (kk == 2) ? A0.z : A0.w;
                float a1 = (kk == 0) ? A1.x : (kk == 1) ? A1.y : (kk == 2) ? A1.z : A1.w;
                float a2 = (kk == 0) ? A2.x : (kk == 1) ? A2.y : (kk == 2) ? A2.z : A2.w;
                float a3 = (kk == 0) ? A3.x : (kk == 1) ? A3.y : (kk == 2) ? A3.z : A3.w;
                acc[0].x = fmaf(a0, w.x, acc[0].x); acc[0].y = fmaf(a0, w.y, acc[0].y);
                acc[0].z = fmaf(a0, w.z, acc[0].z); acc[0].w = fmaf(a0, w.w, acc[0].w);
                acc[1].x = fmaf(a1, w.x, acc[1].x); acc[1].y = fmaf(a1, w.y, acc[1].y);
                acc[1].z = fmaf(a1, w.z, acc[1].z); acc[1].w = fmaf(a1, w.w, acc[1].w);
                acc[2].x = fmaf(a2, w.x, acc[2].x); acc[2].y = fmaf(a2, w.y, acc[2].y);
                acc[2].z = fmaf(a2, w.z, acc[2].z); acc[2].w = fmaf(a2, w.w, acc[2].w);
                acc[3].x = fmaf(a3, w.x, acc[3].x); acc[3].y = fmaf(a3, w.y, acc[3].y);
                acc[3].z = fmaf(a3, w.z, acc[3].z); acc[3].w = fmaf(a3, w.w, acc[3].w);
            }
        }
    }
    #pragma unroll
    for (int i = 0; i < 4; ++i)
        *(float4*)&out[(size_t)(r0 + i) * 6144 + c] = acc[i];
}

extern "C" void kernel_launch(void* const* d_in, const int* in_sizes, int n_in,
                              void* d_out, int out_size, void* d_ws, size_t ws_size,
                              hipStream_t stream) {
    const float* feat  = (const float*)d_in[0];
    const int*   batch = (const int*)d_in[1];
    const float* ln_g  = (const float*)d_in[2];
    const float* ln_b  = (const float*)d_in[3];
    const float* pw    = (const float*)d_in[4];
    const float* pb    = (const float*)d_in[5];
    const float* w1    = (const float*)d_in[6];
    const float* b1    = (const float*)d_in[7];
    const float* w2    = (const float*)d_in[8];
    const float* b2    = (const float*)d_in[9];
    const float* w3    = (const float*)d_in[10];
    const float* b3    = (const float*)d_in[11];
    float* out = (float*)d_out;

    unsigned* pool = (unsigned*)d_ws;            // 128*64 uints
    float* h2buf = (float*)d_ws + BSEG * FEAT;   // 128*512 floats

    // enc(-inf) == 0 under the biased encoding -> memset node, no init kernel
    hipMemsetAsync(pool, 0, BSEG * FEAT * sizeof(unsigned), stream);
    k_segmax<<<NBLK_SEG, 256, 0, stream>>>((const float4*)feat, batch, pool);
    k_mlp<<<BSEG, 1024, 0, stream>>>(pool, ln_g, ln_b, pw, pb, w1, b1, w2, b2, h2buf);
    k_final<<<96, 512, 0, stream>>>(h2buf, w3, b3, out);
}

// Round 4
// 438.990 us; speedup vs baseline: 1.1800x; 1.0765x over previous
//
#include <hip/hip_runtime.h>
#include <hip/hip_bf16.h>

#define N_POINTS 1000000
#define FEAT 64
#define BSEG 128
#define EPS 1e-5f
#define CHUNK 1024
#define NBLK_SEG ((N_POINTS + CHUNK - 1) / CHUNK)   // 977

// ---- biased ordered-uint encoding for float atomic max ----
// enc(x) = ordered(x) - ordered(-inf)  =>  enc(-inf) = 0, so init is memset(0).
#define ENC_BIAS 0x007FFFFFu   // ordered(-inf)

__device__ __forceinline__ unsigned ordered_enc(float f) {
    unsigned u = __float_as_uint(f);
    unsigned o = (u & 0x80000000u) ? ~u : (u | 0x80000000u);
    return o - ENC_BIAS;
}
__device__ __forceinline__ float ordered_dec(unsigned v) {
    unsigned o = v + ENC_BIAS;
    unsigned u = (o & 0x80000000u) ? (o & 0x7fffffffu) : ~o;
    return __uint_as_float(u);
}

// ---- segment max over sorted batch ids ----
__global__ __launch_bounds__(256) void k_segmax(const float4* __restrict__ feat,
                                                const int* __restrict__ batch,
                                                unsigned* __restrict__ pool) {
    __shared__ unsigned short sb[CHUNK];
    __shared__ unsigned spool[4 * FEAT];
    const int t = threadIdx.x;
    const int base = blockIdx.x * CHUNK;
    int rem = N_POINTS - base;
    if (rem > CHUNK) rem = CHUNK;

    for (int i = t; i < CHUNK; i += 256)
        sb[i] = (i < rem) ? (unsigned short)batch[base + i] : (unsigned short)0xFFFF;
    spool[t] = 0u;   // 256 entries == 4*FEAT; 0 == enc(-inf)
    __syncthreads();

    const int seg0 = sb[0];
    const int q = t & 7;
    const int r = t >> 3;

    float4 m0 = make_float4(-INFINITY, -INFINITY, -INFINITY, -INFINITY);
    float4 m1 = m0;
    int cur = -1;

    auto flush = [&](int seg, float4 a, float4 b) {
        unsigned e[8] = { ordered_enc(a.x), ordered_enc(a.y), ordered_enc(a.z), ordered_enc(a.w),
                          ordered_enc(b.x), ordered_enc(b.y), ordered_enc(b.z), ordered_enc(b.w) };
        int slot = seg - seg0;
        if (slot >= 0 && slot < 4) {
            unsigned* p = &spool[slot * FEAT + q * 8];
            #pragma unroll
            for (int j = 0; j < 8; ++j) atomicMax(&p[j], e[j]);
        } else {
            unsigned* p = &pool[seg * FEAT + q * 8];
            #pragma unroll
            for (int j = 0; j < 8; ++j) atomicMax(&p[j], e[j]);
        }
    };

    for (int i = r; i < rem; i += 32) {
        const float4* p = &feat[(size_t)(base + i) * 16 + q * 2];
        float4 v0 = p[0];
        float4 v1 = p[1];
        int seg = sb[i];
        if (seg != cur) {
            if (cur >= 0) flush(cur, m0, m1);
            cur = seg;
            m0 = make_float4(-INFINITY, -INFINITY, -INFINITY, -INFINITY);
            m1 = m0;
        }
        m0.x = fmaxf(m0.x, v0.x); m0.y = fmaxf(m0.y, v0.y);
        m0.z = fmaxf(m0.z, v0.z); m0.w = fmaxf(m0.w, v0.w);
        m1.x = fmaxf(m1.x, v1.x); m1.y = fmaxf(m1.y, v1.y);
        m1.z = fmaxf(m1.z, v1.z); m1.w = fmaxf(m1.w, v1.w);
    }
    if (cur >= 0) flush(cur, m0, m1);
    __syncthreads();

    unsigned v = spool[t];
    if (v != 0u) {
        int slot = t >> 6;
        atomicMax(&pool[(seg0 + slot) * FEAT + (t & 63)], v);
    }
}

// ---- fused LayerNorm + proj + fc1 + fc2 : one block per row, 1024 threads ----
__global__ __launch_bounds__(1024) void k_mlp(const unsigned* __restrict__ pool,
                                              const float* __restrict__ ln_g,
                                              const float* __restrict__ ln_b,
                                              const float* __restrict__ pw,
                                              const float* __restrict__ pb,
                                              const float* __restrict__ w1,
                                              const float* __restrict__ b1,
                                              const float* __restrict__ w2,
                                              const float* __restrict__ b2,
                                              float* __restrict__ h2out) {
    __shared__ float xn[64];
    __shared__ float lat[512];
    __shared__ float h1s[256];
    __shared__ float red[1024];
    const int b = blockIdx.x, t = threadIdx.x;

    if (t < 64) {
        float x = ordered_dec(pool[b * 64 + t]);
        float s = x;
        #pragma unroll
        for (int off = 32; off > 0; off >>= 1) s += __shfl_xor(s, off, 64);
        float mu = s * (1.0f / 64.0f);
        float d = x - mu;
        float s2 = d * d;
        #pragma unroll
        for (int off = 32; off > 0; off >>= 1) s2 += __shfl_xor(s2, off, 64);
        float var = s2 * (1.0f / 64.0f);
        xn[t] = d * rsqrtf(var + EPS) * ln_g[t] + ln_b[t];
    }
    __syncthreads();

    // proj: 512 outputs x 2-way k-split (k=64)
    {
        int o = t & 511, h = t >> 9;
        float a = 0.0f;
        #pragma unroll
        for (int j = 0; j < 32; ++j) {
            int k = h * 32 + j;
            a = fmaf(xn[k], pw[k * 512 + o], a);
        }
        red[t] = a;
    }
    __syncthreads();
    if (t < 512) lat[t] = red[t] + red[t + 512] + pb[t];
    __syncthreads();

    // fc1: 256 outputs x 4-way k-split (k=512)
    {
        int o = t & 255, h = t >> 8;
        float a = 0.0f;
        #pragma unroll 8
        for (int j = 0; j < 128; ++j) {
            int k = h * 128 + j;
            a = fmaf(lat[k], w1[k * 256 + o], a);
        }
        red[t] = a;
    }
    __syncthreads();
    if (t < 256)
        h1s[t] = fmaxf(red[t] + red[t + 256] + red[t + 512] + red[t + 768] + b1[t], 0.0f);
    __syncthreads();

    // fc2: 512 outputs x 2-way k-split (k=256)
    {
        int o = t & 511, h = t >> 9;
        float a = 0.0f;
        #pragma unroll 8
        for (int j = 0; j < 128; ++j) {
            int k = h * 128 + j;
            a = fmaf(h1s[k], w2[k * 512 + o], a);
        }
        red[t] = a;
    }
    __syncthreads();
    if (t < 512)
        h2out[b * 512 + t] = fmaxf(red[t] + red[t + 512] + b2[t], 0.0f);
}

// ---- final GEMM: out[128,6144] = h2[128,512] @ w3[512,6144] + b3 ----
// Grid (96, 2): 64-col panel x 64-row half. 192 blocks x 8 waves = 1.5
// waves/SIMD (vs 0.75 before). Thread = 2 rows x 4 cols; 4096-FMA chain.
// w3 streamed twice total (25 MB, L3-resident) -- traded for 2x parallelism.
#define RS 136
__global__ __launch_bounds__(512) void k_final(const float* __restrict__ h2,
                                               const float* __restrict__ w3,
                                               const float* __restrict__ b3,
                                               float* __restrict__ out) {
    __shared__ float h2s[64 * RS];   // 34.8 KB
    const int t = threadIdx.x;
    const int tx = t & 15;
    const int ty = t >> 4;           // 0..31
    const int c = blockIdx.x * 64 + tx * 4;
    const int rbase = blockIdx.y * 64;
    const int r0 = ty * 2;           // local row pair

    float4 bias = *(const float4*)&b3[c];
    float4 acc0 = bias, acc1 = bias;

    const float4* h2g = (const float4*)h2;
    for (int kc = 0; kc < 512; kc += 128) {
        __syncthreads();
        #pragma unroll
        for (int it = 0; it < 4; ++it) {
            int idx = it * 512 + t;
            int rr = idx >> 5;        // 0..63 local row
            int kq = idx & 31;        // 32 float4 per row-chunk
            float4 v = h2g[(rbase + rr) * 128 + (kc >> 2) + kq];
            *(float4*)&h2s[rr * RS + kq * 4] = v;
        }
        __syncthreads();
        for (int k = 0; k < 128; k += 4) {
            float4 A0 = *(const float4*)&h2s[(r0 + 0) * RS + k];
            float4 A1 = *(const float4*)&h2s[(r0 + 1) * RS + k];
            #pragma unroll
            for (int kk = 0; kk < 4; ++kk) {
                float4 w = *(const float4*)&w3[(size_t)(kc + k + kk) * 6144 + c];
                float a0 = (kk == 0) ? A0.x : (kk == 1) ? A0.y : (kk == 2) ? A0.z : A0.w;
                float a1 = (kk == 0) ? A1.x : (kk == 1) ? A1.y : (kk == 2) ? A1.z : A1.w;
                acc0.x = fmaf(a0, w.x, acc0.x); acc0.y = fmaf(a0, w.y, acc0.y);
                acc0.z = fmaf(a0, w.z, acc0.z); acc0.w = fmaf(a0, w.w, acc0.w);
                acc1.x = fmaf(a1, w.x, acc1.x); acc1.y = fmaf(a1, w.y, acc1.y);
                acc1.z = fmaf(a1, w.z, acc1.z); acc1.w = fmaf(a1, w.w, acc1.w);
            }
        }
    }
    *(float4*)&out[(size_t)(rbase + r0 + 0) * 6144 + c] = acc0;
    *(float4*)&out[(size_t)(rbase + r0 + 1) * 6144 + c] = acc1;
}

extern "C" void kernel_launch(void* const* d_in, const int* in_sizes, int n_in,
                              void* d_out, int out_size, void* d_ws, size_t ws_size,
                              hipStream_t stream) {
    const float* feat  = (const float*)d_in[0];
    const int*   batch = (const int*)d_in[1];
    const float* ln_g  = (const float*)d_in[2];
    const float* ln_b  = (const float*)d_in[3];
    const float* pw    = (const float*)d_in[4];
    const float* pb    = (const float*)d_in[5];
    const float* w1    = (const float*)d_in[6];
    const float* b1    = (const float*)d_in[7];
    const float* w2    = (const float*)d_in[8];
    const float* b2    = (const float*)d_in[9];
    const float* w3    = (const float*)d_in[10];
    const float* b3    = (const float*)d_in[11];
    float* out = (float*)d_out;

    unsigned* pool = (unsigned*)d_ws;            // 128*64 uints
    float* h2buf = (float*)d_ws + BSEG * FEAT;   // 128*512 floats

    // enc(-inf) == 0 under the biased encoding -> memset node, no init kernel
    hipMemsetAsync(pool, 0, BSEG * FEAT * sizeof(unsigned), stream);
    k_segmax<<<NBLK_SEG, 256, 0, stream>>>((const float4*)feat, batch, pool);
    k_mlp<<<BSEG, 1024, 0, stream>>>(pool, ln_g, ln_b, pw, pb, w1, b1, w2, b2, h2buf);
    k_final<<<dim3(96, 2), 512, 0, stream>>>(h2buf, w3, b3, out);
}

// Round 5
// 438.839 us; speedup vs baseline: 1.1804x; 1.0003x over previous
//
#include <hip/hip_runtime.h>
#include <hip/hip_bf16.h>

#define N_POINTS 1000000
#define FEAT 64
#define BSEG 128
#define EPS 1e-5f
#define CHUNK 1024
#define NBLK_SEG ((N_POINTS + CHUNK - 1) / CHUNK)   // 977

// ---- biased ordered-uint encoding for float atomic max ----
// enc(x) = ordered(x) - ordered(-inf)  =>  enc(-inf) = 0, so init is memset(0).
#define ENC_BIAS 0x007FFFFFu   // ordered(-inf)

__device__ __forceinline__ unsigned ordered_enc(float f) {
    unsigned u = __float_as_uint(f);
    unsigned o = (u & 0x80000000u) ? ~u : (u | 0x80000000u);
    return o - ENC_BIAS;
}
__device__ __forceinline__ float ordered_dec(unsigned v) {
    unsigned o = v + ENC_BIAS;
    unsigned u = (o & 0x80000000u) ? (o & 0x7fffffffu) : ~o;
    return __uint_as_float(u);
}

// ---- segment max over sorted batch ids ----
// Thread = (point-lane r 0..31) x (32B feature octet q 0..7).
// TWO independent point streams per thread (i=r, i=r+32; stride 64) with
// separate running-max state -> 4 float4 loads (64 B/lane) in flight.
__global__ __launch_bounds__(256) void k_segmax(const float4* __restrict__ feat,
                                                const int* __restrict__ batch,
                                                unsigned* __restrict__ pool) {
    __shared__ unsigned short sb[CHUNK];
    __shared__ unsigned spool[4 * FEAT];
    const int t = threadIdx.x;
    const int base = blockIdx.x * CHUNK;
    int rem = N_POINTS - base;
    if (rem > CHUNK) rem = CHUNK;

    for (int i = t; i < CHUNK; i += 256)
        sb[i] = (i < rem) ? (unsigned short)batch[base + i] : (unsigned short)0xFFFF;
    spool[t] = 0u;   // 256 entries == 4*FEAT; 0 == enc(-inf)
    __syncthreads();

    const int seg0 = sb[0];
    const int q = t & 7;
    const int r = t >> 3;

    auto flush = [&](int seg, float4 a, float4 b) {
        unsigned e[8] = { ordered_enc(a.x), ordered_enc(a.y), ordered_enc(a.z), ordered_enc(a.w),
                          ordered_enc(b.x), ordered_enc(b.y), ordered_enc(b.z), ordered_enc(b.w) };
        int slot = seg - seg0;
        if (slot >= 0 && slot < 4) {
            unsigned* p = &spool[slot * FEAT + q * 8];
            #pragma unroll
            for (int j = 0; j < 8; ++j) atomicMax(&p[j], e[j]);
        } else {
            unsigned* p = &pool[seg * FEAT + q * 8];
            #pragma unroll
            for (int j = 0; j < 8; ++j) atomicMax(&p[j], e[j]);
        }
    };

    const float4 NEG = make_float4(-INFINITY, -INFINITY, -INFINITY, -INFINITY);
    float4 mA0 = NEG, mA1 = NEG, mB0 = NEG, mB1 = NEG;
    int curA = -1, curB = -1;

    int iA = r, iB = r + 32;
    for (; iB < rem; iA += 64, iB += 64) {
        const float4* pA = &feat[(size_t)(base + iA) * 16 + q * 2];
        const float4* pB = &feat[(size_t)(base + iB) * 16 + q * 2];
        float4 a0 = pA[0], a1 = pA[1];
        float4 b0 = pB[0], b1 = pB[1];
        int sA = sb[iA], sB = sb[iB];

        if (sA != curA) {
            if (curA >= 0) flush(curA, mA0, mA1);
            curA = sA; mA0 = NEG; mA1 = NEG;
        }
        mA0.x = fmaxf(mA0.x, a0.x); mA0.y = fmaxf(mA0.y, a0.y);
        mA0.z = fmaxf(mA0.z, a0.z); mA0.w = fmaxf(mA0.w, a0.w);
        mA1.x = fmaxf(mA1.x, a1.x); mA1.y = fmaxf(mA1.y, a1.y);
        mA1.z = fmaxf(mA1.z, a1.z); mA1.w = fmaxf(mA1.w, a1.w);

        if (sB != curB) {
            if (curB >= 0) flush(curB, mB0, mB1);
            curB = sB; mB0 = NEG; mB1 = NEG;
        }
        mB0.x = fmaxf(mB0.x, b0.x); mB0.y = fmaxf(mB0.y, b0.y);
        mB0.z = fmaxf(mB0.z, b0.z); mB0.w = fmaxf(mB0.w, b0.w);
        mB1.x = fmaxf(mB1.x, b1.x); mB1.y = fmaxf(mB1.y, b1.y);
        mB1.z = fmaxf(mB1.z, b1.z); mB1.w = fmaxf(mB1.w, b1.w);
    }
    if (iA < rem) {   // tail point for stream A (last partial chunk only)
        const float4* pA = &feat[(size_t)(base + iA) * 16 + q * 2];
        float4 a0 = pA[0], a1 = pA[1];
        int sA = sb[iA];
        if (sA != curA) {
            if (curA >= 0) flush(curA, mA0, mA1);
            curA = sA; mA0 = NEG; mA1 = NEG;
        }
        mA0.x = fmaxf(mA0.x, a0.x); mA0.y = fmaxf(mA0.y, a0.y);
        mA0.z = fmaxf(mA0.z, a0.z); mA0.w = fmaxf(mA0.w, a0.w);
        mA1.x = fmaxf(mA1.x, a1.x); mA1.y = fmaxf(mA1.y, a1.y);
        mA1.z = fmaxf(mA1.z, a1.z); mA1.w = fmaxf(mA1.w, a1.w);
    }
    if (curA >= 0) flush(curA, mA0, mA1);
    if (curB >= 0) flush(curB, mB0, mB1);
    __syncthreads();

    unsigned v = spool[t];
    if (v != 0u) {
        int slot = t >> 6;
        atomicMax(&pool[(seg0 + slot) * FEAT + (t & 63)], v);
    }
}

// ---- fused LayerNorm + proj + fc1 + fc2 : one block per row, 1024 threads ----
__global__ __launch_bounds__(1024) void k_mlp(const unsigned* __restrict__ pool,
                                              const float* __restrict__ ln_g,
                                              const float* __restrict__ ln_b,
                                              const float* __restrict__ pw,
                                              const float* __restrict__ pb,
                                              const float* __restrict__ w1,
                                              const float* __restrict__ b1,
                                              const float* __restrict__ w2,
                                              const float* __restrict__ b2,
                                              float* __restrict__ h2out) {
    __shared__ float xn[64];
    __shared__ float lat[512];
    __shared__ float h1s[256];
    __shared__ float red[1024];
    const int b = blockIdx.x, t = threadIdx.x;

    if (t < 64) {
        float x = ordered_dec(pool[b * 64 + t]);
        float s = x;
        #pragma unroll
        for (int off = 32; off > 0; off >>= 1) s += __shfl_xor(s, off, 64);
        float mu = s * (1.0f / 64.0f);
        float d = x - mu;
        float s2 = d * d;
        #pragma unroll
        for (int off = 32; off > 0; off >>= 1) s2 += __shfl_xor(s2, off, 64);
        float var = s2 * (1.0f / 64.0f);
        xn[t] = d * rsqrtf(var + EPS) * ln_g[t] + ln_b[t];
    }
    __syncthreads();

    // proj: 512 outputs x 2-way k-split (k=64)
    {
        int o = t & 511, h = t >> 9;
        float a = 0.0f;
        #pragma unroll
        for (int j = 0; j < 32; ++j) {
            int k = h * 32 + j;
            a = fmaf(xn[k], pw[k * 512 + o], a);
        }
        red[t] = a;
    }
    __syncthreads();
    if (t < 512) lat[t] = red[t] + red[t + 512] + pb[t];
    __syncthreads();

    // fc1: 256 outputs x 4-way k-split (k=512)
    {
        int o = t & 255, h = t >> 8;
        float a = 0.0f;
        #pragma unroll 8
        for (int j = 0; j < 128; ++j) {
            int k = h * 128 + j;
            a = fmaf(lat[k], w1[k * 256 + o], a);
        }
        red[t] = a;
    }
    __syncthreads();
    if (t < 256)
        h1s[t] = fmaxf(red[t] + red[t + 256] + red[t + 512] + red[t + 768] + b1[t], 0.0f);
    __syncthreads();

    // fc2: 512 outputs x 2-way k-split (k=256)
    {
        int o = t & 511, h = t >> 9;
        float a = 0.0f;
        #pragma unroll 8
        for (int j = 0; j < 128; ++j) {
            int k = h * 128 + j;
            a = fmaf(h1s[k], w2[k * 512 + o], a);
        }
        red[t] = a;
    }
    __syncthreads();
    if (t < 512)
        h2out[b * 512 + t] = fmaxf(red[t] + red[t + 512] + b2[t], 0.0f);
}

// ---- final GEMM: out[128,6144] = h2[128,512] @ w3[512,6144] + b3 ----
#define RS 136
__global__ __launch_bounds__(512) void k_final(const float* __restrict__ h2,
                                               const float* __restrict__ w3,
                                               const float* __restrict__ b3,
                                               float* __restrict__ out) {
    __shared__ float h2s[64 * RS];   // 34.8 KB
    const int t = threadIdx.x;
    const int tx = t & 15;
    const int ty = t >> 4;           // 0..31
    const int c = blockIdx.x * 64 + tx * 4;
    const int rbase = blockIdx.y * 64;
    const int r0 = ty * 2;           // local row pair

    float4 bias = *(const float4*)&b3[c];
    float4 acc0 = bias, acc1 = bias;

    const float4* h2g = (const float4*)h2;
    for (int kc = 0; kc < 512; kc += 128) {
        __syncthreads();
        #pragma unroll
        for (int it = 0; it < 4; ++it) {
            int idx = it * 512 + t;
            int rr = idx >> 5;        // 0..63 local row
            int kq = idx & 31;        // 32 float4 per row-chunk
            float4 v = h2g[(rbase + rr) * 128 + (kc >> 2) + kq];
            *(float4*)&h2s[rr * RS + kq * 4] = v;
        }
        __syncthreads();
        for (int k = 0; k < 128; k += 4) {
            float4 A0 = *(const float4*)&h2s[(r0 + 0) * RS + k];
            float4 A1 = *(const float4*)&h2s[(r0 + 1) * RS + k];
            #pragma unroll
            for (int kk = 0; kk < 4; ++kk) {
                float4 w = *(const float4*)&w3[(size_t)(kc + k + kk) * 6144 + c];
                float a0 = (kk == 0) ? A0.x : (kk == 1) ? A0.y : (kk == 2) ? A0.z : A0.w;
                float a1 = (kk == 0) ? A1.x : (kk == 1) ? A1.y : (kk == 2) ? A1.z : A1.w;
                acc0.x = fmaf(a0, w.x, acc0.x); acc0.y = fmaf(a0, w.y, acc0.y);
                acc0.z = fmaf(a0, w.z, acc0.z); acc0.w = fmaf(a0, w.w, acc0.w);
                acc1.x = fmaf(a1, w.x, acc1.x); acc1.y = fmaf(a1, w.y, acc1.y);
                acc1.z = fmaf(a1, w.z, acc1.z); acc1.w = fmaf(a1, w.w, acc1.w);
            }
        }
    }
    *(float4*)&out[(size_t)(rbase + r0 + 0) * 6144 + c] = acc0;
    *(float4*)&out[(size_t)(rbase + r0 + 1) * 6144 + c] = acc1;
}

extern "C" void kernel_launch(void* const* d_in, const int* in_sizes, int n_in,
                              void* d_out, int out_size, void* d_ws, size_t ws_size,
                              hipStream_t stream) {
    const float* feat  = (const float*)d_in[0];
    const int*   batch = (const int*)d_in[1];
    const float* ln_g  = (const float*)d_in[2];
    const float* ln_b  = (const float*)d_in[3];
    const float* pw    = (const float*)d_in[4];
    const float* pb    = (const float*)d_in[5];
    const float* w1    = (const float*)d_in[6];
    const float* b1    = (const float*)d_in[7];
    const float* w2    = (const float*)d_in[8];
    const float* b2    = (const float*)d_in[9];
    const float* w3    = (const float*)d_in[10];
    const float* b3    = (const float*)d_in[11];
    float* out = (float*)d_out;

    unsigned* pool = (unsigned*)d_ws;            // 128*64 uints
    float* h2buf = (float*)d_ws + BSEG * FEAT;   // 128*512 floats

    // enc(-inf) == 0 under the biased encoding -> memset node, no init kernel
    hipMemsetAsync(pool, 0, BSEG * FEAT * sizeof(unsigned), stream);
    k_segmax<<<NBLK_SEG, 256, 0, stream>>>((const float4*)feat, batch, pool);
    k_mlp<<<BSEG, 1024, 0, stream>>>(pool, ln_g, ln_b, pw, pb, w1, b1, w2, b2, h2buf);
    k_final<<<dim3(96, 2), 512, 0, stream>>>(h2buf, w3, b3, out);
}